// Round 2
// baseline (501.522 us; speedup 1.0000x reference)
//
#include <hip/hip_runtime.h>
#include <math.h>

#define NUM_E   100000
#define GAMMA_F 12.0f
#define EMB_RANGE_F 0.21875f                       // (12+2)/64
#define INV_TWO_EMB (1.0f / (2.0f * EMB_RANGE_F))  // rev = r * this = phase/(2pi)

typedef float v4f __attribute__((ext_vector_type(4)));
typedef float v2f __attribute__((ext_vector_type(2)));

// ---- packed-f32 VALU (VOP3P): 2 dims per instruction ----
static __device__ __forceinline__ v2f pk_sub(v2f a, v2f b) {
    v2f d;
    asm("v_pk_add_f32 %0, %1, %2 neg_lo:[0,1] neg_hi:[0,1]"
        : "=v"(d) : "v"(a), "v"(b));
    return d;
}
static __device__ __forceinline__ v2f pk_mul(v2f a, v2f b) {
    v2f d;
    asm("v_pk_mul_f32 %0, %1, %2" : "=v"(d) : "v"(a), "v"(b));
    return d;
}
static __device__ __forceinline__ v2f pk_fma(v2f a, v2f b, v2f c) {
    v2f d;
    asm("v_pk_fma_f32 %0, %1, %2, %3" : "=v"(d) : "v"(a), "v"(b), "v"(c));
    return d;
}
static __device__ __forceinline__ float sq2(v2f dx, v2f dy) {
    v2f sq = pk_fma(dy, dy, pk_mul(dx, dx));
    return __builtin_amdgcn_sqrtf(sq.x) + __builtin_amdgcn_sqrtf(sq.y);
}
static __device__ __forceinline__ v2f lo2(v4f v) { return __builtin_shufflevector(v, v, 0, 1); }
static __device__ __forceinline__ v2f hi2(v4f v) { return __builtin_shufflevector(v, v, 2, 3); }

// cross-lane add via DPP (VALU pipe, no DS, no lgkm wait)
// 0xB1 = quad_perm [1,0,3,2] (xor1), 0x4E = quad_perm [2,3,0,1] (xor2),
// 0x141 = row_half_mirror: valid xor4 substitute AFTER xor1+xor2 (all lanes of
// each quad hold equal values, and 7-dg lands in the dg^4 quad of the same bg).
template <int CTRL>
static __device__ __forceinline__ float dpp_xor_add(float x) {
    int y = __builtin_amdgcn_update_dpp(0, __float_as_int(x), CTRL, 0xF, 0xF, true);
    return x + __int_as_float(y);
}

// R8: single fused kernel, R6 tile structure.
//  - Prologue: block computes the 32x128 rot table (~0.6us chip-wide redundant)
//    into LDS, layout [kb*4+part][lane][4] so main-loop reads are ds_read_b128
//    at lane*16B: lane-linear = conflict-free. Wave wv computes kb=wv rows.
//  - Main loop: entity rows read DIRECT from global (each row is consumed by
//    exactly one wave - R6's LDS staging was pure overhead). 8 waves/SIMD hide
//    the latency (launch_bounds(256,8): VGPR<=64, proven enough by R6's 56).
//  - Reduce: 3 DPP adds on the VALU pipe, zero DS ops.
//  - Store: register transpose (3 cndmask) + one dwordx4 per 4 entities per
//    lane-with-dg<4 -> same 16B-coalesced pattern as R6 (13MB WRITE_SIZE).
__global__ __launch_bounds__(256, 8) void rotate_dist_fused(
        const int*   __restrict__ facts,
        const float* __restrict__ ent,
        const float* __restrict__ rel,
        float*       __restrict__ out) {
    __shared__ __align__(16) float rot_lds[16 * 64 * 4];   // 16 KB

    const int t    = threadIdx.x;
    const int lane = t & 63;
    const int wv   = t >> 6;            // doubles as kb in the prologue
    const int bg   = lane >> 3;         // batches 4bg..4bg+3
    const int dg   = lane & 7;          // dims 8dg..8dg+7

    // ---- prologue: rot table into LDS ----
    {
        const int b  = bg * 4 + wv;     // this thread's batch row
        const int f0 = facts[b * 3 + 0];
        const int f1 = facts[b * 3 + 1];
        const float* hp = ent + (size_t)f0 * 128 + dg * 8;
        const float* rp = rel + (size_t)f1 * 64  + dg * 8;
        float hre[8], him[8], ph[8];
        *(v4f*)&hre[0] = *(const v4f*)(hp);
        *(v4f*)&hre[4] = *(const v4f*)(hp + 4);
        *(v4f*)&him[0] = *(const v4f*)(hp + 64);
        *(v4f*)&him[4] = *(const v4f*)(hp + 68);
        *(v4f*)&ph[0]  = *(const v4f*)(rp);
        *(v4f*)&ph[4]  = *(const v4f*)(rp + 4);
        float rr[8], ri[8];
#pragma unroll
        for (int j = 0; j < 8; ++j) {
            float rev = ph[j] * INV_TWO_EMB;         // phase/(2pi) in [-0.5,0.5]
            float s = __builtin_amdgcn_sinf(rev);    // v_sin_f32: revolutions
            float c = __builtin_amdgcn_cosf(rev);
            rr[j] = hre[j] * c - him[j] * s;
            ri[j] = hre[j] * s + him[j] * c;
        }
        // layout: ((kb*4 + part)*64 + lane)*4 ; parts: re-lo, re-hi, im-lo, im-hi
        float* wbase = rot_lds + (wv * 4) * 256 + lane * 4;
        *(v4f*)(wbase + 0 * 256) = *(const v4f*)&rr[0];
        *(v4f*)(wbase + 1 * 256) = *(const v4f*)&rr[4];
        *(v4f*)(wbase + 2 * 256) = *(const v4f*)&ri[0];
        *(v4f*)(wbase + 3 * 256) = *(const v4f*)&ri[4];
    }
    __syncthreads();

    const int e0 = blockIdx.x * 32 + wv * 8;
    const float* rbase = rot_lds + lane * 4;
    float* obase = out + (size_t)(bg * 4 + (dg & 3)) * NUM_E + e0;

#pragma unroll 1
    for (int grp = 0; grp < 2; ++grp) {
        // rot fragments from LDS (conflict-free b128; compiler may remat per use)
        v2f RR[4][4], RI[4][4];
#pragma unroll
        for (int kb = 0; kb < 4; ++kb) {
            v4f a = *(const v4f*)(rbase + (kb * 4 + 0) * 256);
            v4f b = *(const v4f*)(rbase + (kb * 4 + 1) * 256);
            v4f c = *(const v4f*)(rbase + (kb * 4 + 2) * 256);
            v4f d = *(const v4f*)(rbase + (kb * 4 + 3) * 256);
            RR[kb][0] = lo2(a); RR[kb][1] = hi2(a); RR[kb][2] = lo2(b); RR[kb][3] = hi2(b);
            RI[kb][0] = lo2(c); RI[kb][1] = hi2(c); RI[kb][2] = lo2(d); RI[kb][3] = hi2(d);
        }

        float p[4][4];                   // [entity in group][batch kb]
#pragma unroll
        for (int i = 0; i < 4; ++i) {
            const float* ebase = ent + (size_t)(e0 + grp * 4 + i) * 128 + dg * 8;
            v4f er0 = *(const v4f*)(ebase);
            v4f er1 = *(const v4f*)(ebase + 4);
            v4f ei0 = *(const v4f*)(ebase + 64);
            v4f ei1 = *(const v4f*)(ebase + 68);
            v2f e2[4] = { lo2(er0), hi2(er0), lo2(er1), hi2(er1) };
            v2f i2[4] = { lo2(ei0), hi2(ei0), lo2(ei1), hi2(ei1) };
#pragma unroll
            for (int kb = 0; kb < 4; ++kb) {
                float s0 = sq2(pk_sub(RR[kb][0], e2[0]), pk_sub(RI[kb][0], i2[0]));
                float s1 = sq2(pk_sub(RR[kb][1], e2[1]), pk_sub(RI[kb][1], i2[1]));
                float s2 = sq2(pk_sub(RR[kb][2], e2[2]), pk_sub(RI[kb][2], i2[2]));
                float s3 = sq2(pk_sub(RR[kb][3], e2[3]), pk_sub(RI[kb][3], i2[3]));
                p[i][kb] = (s0 + s1) + (s2 + s3);
            }
        }

        // reduce over dg (all-VALU) + register transpose + coalesced store
        float vout[4];
#pragma unroll
        for (int i = 0; i < 4; ++i) {
            float r[4];
#pragma unroll
            for (int kb = 0; kb < 4; ++kb) {
                float v = p[i][kb];
                v = dpp_xor_add<0xB1>(v);            // xor1
                v = dpp_xor_add<0x4E>(v);            // xor2
                v = dpp_xor_add<0x141>(v);           // xor4 via row_half_mirror
                r[kb] = v;
            }
            float sel = (dg == 0) ? r[0] : (dg == 1) ? r[1]
                      : (dg == 2) ? r[2] : r[3];
            vout[i] = GAMMA_F - sel;
        }
        if (dg < 4) {
            v4f vv; vv.x = vout[0]; vv.y = vout[1]; vv.z = vout[2]; vv.w = vout[3];
            *(v4f*)(obase + grp * 4) = vv;           // 16B segment per batch row
        }
    }
}

extern "C" void kernel_launch(void* const* d_in, const int* in_sizes, int n_in,
                              void* d_out, int out_size, void* d_ws, size_t ws_size,
                              hipStream_t stream) {
    const int*   facts = (const int*)d_in[0];
    const float* ent   = (const float*)d_in[1];
    const float* rel   = (const float*)d_in[2];
    float*       out   = (float*)d_out;
    (void)d_ws; (void)ws_size;

    // 3125 blocks x 32 entities/block = 100000 exactly
    rotate_dist_fused<<<dim3(NUM_E / 32), dim3(256), 0, stream>>>(facts, ent, rel, out);
}

// Round 3
// 254.048 us; speedup vs baseline: 1.9741x; 1.9741x over previous
//
#include <hip/hip_runtime.h>
#include <math.h>

#define NUM_E   100000
#define GAMMA_F 12.0f
#define EMB_RANGE_F 0.21875f                       // (12+2)/64
#define INV_TWO_EMB (1.0f / (2.0f * EMB_RANGE_F))  // rev = r * this = phase/(2pi)

typedef float v4f __attribute__((ext_vector_type(4)));
typedef float v2f __attribute__((ext_vector_type(2)));

// ---- packed-f32 VALU (VOP3P): 2 dims per instruction ----
static __device__ __forceinline__ v2f pk_sub(v2f a, v2f b) {
    v2f d;
    asm("v_pk_add_f32 %0, %1, %2 neg_lo:[0,1] neg_hi:[0,1]"
        : "=v"(d) : "v"(a), "v"(b));
    return d;
}
static __device__ __forceinline__ v2f pk_mul(v2f a, v2f b) {
    v2f d;
    asm("v_pk_mul_f32 %0, %1, %2" : "=v"(d) : "v"(a), "v"(b));
    return d;
}
static __device__ __forceinline__ v2f pk_fma(v2f a, v2f b, v2f c) {
    v2f d;
    asm("v_pk_fma_f32 %0, %1, %2, %3" : "=v"(d) : "v"(a), "v"(b), "v"(c));
    return d;
}
static __device__ __forceinline__ float sq2(v2f dx, v2f dy) {
    v2f sq = pk_fma(dy, dy, pk_mul(dx, dx));
    return __builtin_amdgcn_sqrtf(sq.x) + __builtin_amdgcn_sqrtf(sq.y);
}
static __device__ __forceinline__ v2f lo2(v4f v) { return __builtin_shufflevector(v, v, 0, 1); }
static __device__ __forceinline__ v2f hi2(v4f v) { return __builtin_shufflevector(v, v, 2, 3); }

// cross-lane add via DPP (VALU pipe, no DS, no lgkm wait)
// 0xB1 = quad_perm [1,0,3,2] (xor1), 0x4E = quad_perm [2,3,0,1] (xor2),
// 0x141 = row_half_mirror: valid xor4 substitute AFTER xor1+xor2 (all lanes of
// each quad hold equal values, and 7-dg lands in the dg^4 quad of the same bg).
template <int CTRL>
static __device__ __forceinline__ float dpp_xor_add(float x) {
    int y = __builtin_amdgcn_update_dpp(0, __float_as_int(x), CTRL, 0xF, 0xF, true);
    return x + __int_as_float(y);
}

// R9 = R8 structure with the spill fixed.
// R8's __launch_bounds__(256,8) capped VGPR at 64 -> compiler allocated 32 and
// spilled RR/RI+p to scratch: WRITE_SIZE 13MB->664MB, FETCH 25MB->846MB, 459us.
// This kernel's live set (~110 VGPR) needs the 128-VGPR / 4-waves-per-SIMD
// envelope -> __launch_bounds__(256,4). Everything else unchanged vs R8:
//  - fused sin/cos prologue into lane-linear LDS rot table (conflict-free b128)
//  - entity rows direct from global (each row consumed by exactly one wave)
//  - reduction entirely on the VALU pipe via DPP (no ds_swizzle, no lgkm wait)
//  - register transpose + 16B-coalesced dwordx4 stores (13MB write, no scratch)
__global__ __launch_bounds__(256, 4) void rotate_dist_fused(
        const int*   __restrict__ facts,
        const float* __restrict__ ent,
        const float* __restrict__ rel,
        float*       __restrict__ out) {
    __shared__ __align__(16) float rot_lds[16 * 64 * 4];   // 16 KB

    const int t    = threadIdx.x;
    const int lane = t & 63;
    const int wv   = t >> 6;            // doubles as kb in the prologue
    const int bg   = lane >> 3;         // batches 4bg..4bg+3
    const int dg   = lane & 7;          // dims 8dg..8dg+7

    // ---- prologue: rot table into LDS ----
    {
        const int b  = bg * 4 + wv;     // this thread's batch row
        const int f0 = facts[b * 3 + 0];
        const int f1 = facts[b * 3 + 1];
        const float* hp = ent + (size_t)f0 * 128 + dg * 8;
        const float* rp = rel + (size_t)f1 * 64  + dg * 8;
        float hre[8], him[8], ph[8];
        *(v4f*)&hre[0] = *(const v4f*)(hp);
        *(v4f*)&hre[4] = *(const v4f*)(hp + 4);
        *(v4f*)&him[0] = *(const v4f*)(hp + 64);
        *(v4f*)&him[4] = *(const v4f*)(hp + 68);
        *(v4f*)&ph[0]  = *(const v4f*)(rp);
        *(v4f*)&ph[4]  = *(const v4f*)(rp + 4);
        float rr[8], ri[8];
#pragma unroll
        for (int j = 0; j < 8; ++j) {
            float rev = ph[j] * INV_TWO_EMB;         // phase/(2pi) in [-0.5,0.5]
            float s = __builtin_amdgcn_sinf(rev);    // v_sin_f32: revolutions
            float c = __builtin_amdgcn_cosf(rev);
            rr[j] = hre[j] * c - him[j] * s;
            ri[j] = hre[j] * s + him[j] * c;
        }
        // layout: ((kb*4 + part)*64 + lane)*4 ; parts: re-lo, re-hi, im-lo, im-hi
        float* wbase = rot_lds + (wv * 4) * 256 + lane * 4;
        *(v4f*)(wbase + 0 * 256) = *(const v4f*)&rr[0];
        *(v4f*)(wbase + 1 * 256) = *(const v4f*)&rr[4];
        *(v4f*)(wbase + 2 * 256) = *(const v4f*)&ri[0];
        *(v4f*)(wbase + 3 * 256) = *(const v4f*)&ri[4];
    }
    __syncthreads();

    const int e0 = blockIdx.x * 32 + wv * 8;
    const float* rbase = rot_lds + lane * 4;
    float* obase = out + (size_t)(bg * 4 + (dg & 3)) * NUM_E + e0;

#pragma unroll 1
    for (int grp = 0; grp < 2; ++grp) {
        // rot fragments from LDS (loop-invariant; LICM hoists once regs allow)
        v2f RR[4][4], RI[4][4];
#pragma unroll
        for (int kb = 0; kb < 4; ++kb) {
            v4f a = *(const v4f*)(rbase + (kb * 4 + 0) * 256);
            v4f b = *(const v4f*)(rbase + (kb * 4 + 1) * 256);
            v4f c = *(const v4f*)(rbase + (kb * 4 + 2) * 256);
            v4f d = *(const v4f*)(rbase + (kb * 4 + 3) * 256);
            RR[kb][0] = lo2(a); RR[kb][1] = hi2(a); RR[kb][2] = lo2(b); RR[kb][3] = hi2(b);
            RI[kb][0] = lo2(c); RI[kb][1] = hi2(c); RI[kb][2] = lo2(d); RI[kb][3] = hi2(d);
        }

        float p[4][4];                   // [entity in group][batch kb]
#pragma unroll
        for (int i = 0; i < 4; ++i) {
            const float* ebase = ent + (size_t)(e0 + grp * 4 + i) * 128 + dg * 8;
            v4f er0 = *(const v4f*)(ebase);
            v4f er1 = *(const v4f*)(ebase + 4);
            v4f ei0 = *(const v4f*)(ebase + 64);
            v4f ei1 = *(const v4f*)(ebase + 68);
            v2f e2[4] = { lo2(er0), hi2(er0), lo2(er1), hi2(er1) };
            v2f i2[4] = { lo2(ei0), hi2(ei0), lo2(ei1), hi2(ei1) };
#pragma unroll
            for (int kb = 0; kb < 4; ++kb) {
                float s0 = sq2(pk_sub(RR[kb][0], e2[0]), pk_sub(RI[kb][0], i2[0]));
                float s1 = sq2(pk_sub(RR[kb][1], e2[1]), pk_sub(RI[kb][1], i2[1]));
                float s2 = sq2(pk_sub(RR[kb][2], e2[2]), pk_sub(RI[kb][2], i2[2]));
                float s3 = sq2(pk_sub(RR[kb][3], e2[3]), pk_sub(RI[kb][3], i2[3]));
                p[i][kb] = (s0 + s1) + (s2 + s3);
            }
        }

        // reduce over dg (all-VALU) + register transpose + coalesced store
        float vout[4];
#pragma unroll
        for (int i = 0; i < 4; ++i) {
            float r[4];
#pragma unroll
            for (int kb = 0; kb < 4; ++kb) {
                float v = p[i][kb];
                v = dpp_xor_add<0xB1>(v);            // xor1
                v = dpp_xor_add<0x4E>(v);            // xor2
                v = dpp_xor_add<0x141>(v);           // xor4 via row_half_mirror
                r[kb] = v;
            }
            float sel = (dg == 0) ? r[0] : (dg == 1) ? r[1]
                      : (dg == 2) ? r[2] : r[3];
            vout[i] = GAMMA_F - sel;
        }
        if (dg < 4) {
            v4f vv; vv.x = vout[0]; vv.y = vout[1]; vv.z = vout[2]; vv.w = vout[3];
            *(v4f*)(obase + grp * 4) = vv;           // 16B segment per batch row
        }
    }
}

extern "C" void kernel_launch(void* const* d_in, const int* in_sizes, int n_in,
                              void* d_out, int out_size, void* d_ws, size_t ws_size,
                              hipStream_t stream) {
    const int*   facts = (const int*)d_in[0];
    const float* ent   = (const float*)d_in[1];
    const float* rel   = (const float*)d_in[2];
    float*       out   = (float*)d_out;
    (void)d_ws; (void)ws_size;

    // 3125 blocks x 32 entities/block = 100000 exactly
    rotate_dist_fused<<<dim3(NUM_E / 32), dim3(256), 0, stream>>>(facts, ent, rel, out);
}

// Round 4
// 121.494 us; speedup vs baseline: 4.1280x; 2.0910x over previous
//
#include <hip/hip_runtime.h>
#include <math.h>

#define NUM_E   100000
#define GAMMA_F 12.0f
#define EMB_RANGE_F 0.21875f                       // (12+2)/64
#define INV_TWO_EMB (1.0f / (2.0f * EMB_RANGE_F))  // rev = r * this = phase/(2pi)

typedef float v4f __attribute__((ext_vector_type(4)));
typedef float v2f __attribute__((ext_vector_type(2)));

// ---- packed-f32 VALU (VOP3P): 2 dims per instruction ----
static __device__ __forceinline__ v2f pk_sub(v2f a, v2f b) {
    v2f d;
    asm("v_pk_add_f32 %0, %1, %2 neg_lo:[0,1] neg_hi:[0,1]"
        : "=v"(d) : "v"(a), "v"(b));
    return d;
}
static __device__ __forceinline__ v2f pk_mul(v2f a, v2f b) {
    v2f d;
    asm("v_pk_mul_f32 %0, %1, %2" : "=v"(d) : "v"(a), "v"(b));
    return d;
}
static __device__ __forceinline__ v2f pk_fma(v2f a, v2f b, v2f c) {
    v2f d;
    asm("v_pk_fma_f32 %0, %1, %2, %3" : "=v"(d) : "v"(a), "v"(b), "v"(c));
    return d;
}
static __device__ __forceinline__ float sq2(v2f dx, v2f dy) {
    v2f sq = pk_fma(dy, dy, pk_mul(dx, dx));
    return __builtin_amdgcn_sqrtf(sq.x) + __builtin_amdgcn_sqrtf(sq.y);
}
static __device__ __forceinline__ v2f lo2(v4f v) { return __builtin_shufflevector(v, v, 0, 1); }
static __device__ __forceinline__ v2f hi2(v4f v) { return __builtin_shufflevector(v, v, 2, 3); }

// cross-lane add via DPP (VALU pipe, no DS, no lgkm wait)
// 0xB1 = quad_perm [1,0,3,2] (xor1), 0x4E = quad_perm [2,3,0,1] (xor2),
// 0x141 = row_half_mirror: valid xor4 substitute AFTER xor1+xor2 (verified
// passing in R8/R9).
template <int CTRL>
static __device__ __forceinline__ float dpp_xor_add(float x) {
    int y = __builtin_amdgcn_update_dpp(0, __float_as_int(x), CTRL, 0xF, 0xF, true);
    return x + __int_as_float(y);
}

// R10: fix the VGPR cap + shrink the live set.
// Empirical hipcc rule from R6-R9: __launch_bounds__(256,w) caps VGPRs at
// 256/w (NOT 512/w): (256,8)->32, (256,4)->64 -- both observed. R9's ~105-reg
// live set spilled to scratch under the 64 cap (WRITE 352MB, 17% VALUBusy).
//  - __launch_bounds__(256,2): cap 128. HW occupancy follows ACTUAL allocation
//    (~105 VGPR -> 4 waves/SIMD, same as R6).
//  - Reduction interleaved per-entity: p[4][4] (16 live floats across two loop
//    nests) -> r[4]+vout[4], saving ~12 registers.
//  - RR/RI hoisted out of the grp loop (read LDS once, stay resident).
//  - Prologue uses v4f values + constant-index components (no float[8] arrays
//    behind pointer casts -> no alloca hazard).
__global__ __launch_bounds__(256, 2) void rotate_dist_fused(
        const int*   __restrict__ facts,
        const float* __restrict__ ent,
        const float* __restrict__ rel,
        float*       __restrict__ out) {
    __shared__ __align__(16) float rot_lds[16 * 64 * 4];   // 16 KB

    const int t    = threadIdx.x;
    const int lane = t & 63;
    const int wv   = t >> 6;            // doubles as kb in the prologue
    const int bg   = lane >> 3;         // batches 4bg..4bg+3
    const int dg   = lane & 7;          // dims 8dg..8dg+7

    // ---- prologue: rot table into LDS (wave wv computes kb=wv slots) ----
    {
        const int b  = bg * 4 + wv;     // this thread's batch row
        const int f0 = facts[b * 3 + 0];
        const int f1 = facts[b * 3 + 1];
        const float* hp = ent + (size_t)f0 * 128 + dg * 8;
        const float* rp = rel + (size_t)f1 * 64  + dg * 8;
        v4f hre0 = *(const v4f*)(hp);
        v4f hre1 = *(const v4f*)(hp + 4);
        v4f him0 = *(const v4f*)(hp + 64);
        v4f him1 = *(const v4f*)(hp + 68);
        v4f ph0  = *(const v4f*)(rp);
        v4f ph1  = *(const v4f*)(rp + 4);
        v4f rr0, rr1, ri0, ri1;
#pragma unroll
        for (int j = 0; j < 4; ++j) {
            float rev0 = ph0[j] * INV_TWO_EMB;       // phase/(2pi) in [-0.5,0.5]
            float s0 = __builtin_amdgcn_sinf(rev0);  // v_sin_f32: revolutions
            float c0 = __builtin_amdgcn_cosf(rev0);
            rr0[j] = hre0[j] * c0 - him0[j] * s0;
            ri0[j] = hre0[j] * s0 + him0[j] * c0;
            float rev1 = ph1[j] * INV_TWO_EMB;
            float s1 = __builtin_amdgcn_sinf(rev1);
            float c1 = __builtin_amdgcn_cosf(rev1);
            rr1[j] = hre1[j] * c1 - him1[j] * s1;
            ri1[j] = hre1[j] * s1 + him1[j] * c1;
        }
        // layout: ((kb*4 + part)*64 + lane)*4 ; parts: re-lo, re-hi, im-lo, im-hi
        float* wbase = rot_lds + (wv * 4) * 256 + lane * 4;
        *(v4f*)(wbase + 0 * 256) = rr0;
        *(v4f*)(wbase + 1 * 256) = rr1;
        *(v4f*)(wbase + 2 * 256) = ri0;
        *(v4f*)(wbase + 3 * 256) = ri1;
    }
    __syncthreads();

    const int e0 = blockIdx.x * 32 + wv * 8;
    const float* rbase = rot_lds + lane * 4;
    float* obase = out + (size_t)(bg * 4 + (dg & 3)) * NUM_E + e0;

    // rot fragments LDS -> registers ONCE (64 VGPRs, resident for the kernel)
    v2f RR[4][4], RI[4][4];
#pragma unroll
    for (int kb = 0; kb < 4; ++kb) {
        v4f a = *(const v4f*)(rbase + (kb * 4 + 0) * 256);
        v4f b = *(const v4f*)(rbase + (kb * 4 + 1) * 256);
        v4f c = *(const v4f*)(rbase + (kb * 4 + 2) * 256);
        v4f d = *(const v4f*)(rbase + (kb * 4 + 3) * 256);
        RR[kb][0] = lo2(a); RR[kb][1] = hi2(a); RR[kb][2] = lo2(b); RR[kb][3] = hi2(b);
        RI[kb][0] = lo2(c); RI[kb][1] = hi2(c); RI[kb][2] = lo2(d); RI[kb][3] = hi2(d);
    }

#pragma unroll 1
    for (int grp = 0; grp < 2; ++grp) {
        v4f vout;
#pragma unroll
        for (int i = 0; i < 4; ++i) {
            const float* ebase = ent + (size_t)(e0 + grp * 4 + i) * 128 + dg * 8;
            v4f er0 = *(const v4f*)(ebase);
            v4f er1 = *(const v4f*)(ebase + 4);
            v4f ei0 = *(const v4f*)(ebase + 64);
            v4f ei1 = *(const v4f*)(ebase + 68);
            v2f e2[4] = { lo2(er0), hi2(er0), lo2(er1), hi2(er1) };
            v2f i2[4] = { lo2(ei0), hi2(ei0), lo2(ei1), hi2(ei1) };
            float r[4];
#pragma unroll
            for (int kb = 0; kb < 4; ++kb) {
                float s0 = sq2(pk_sub(RR[kb][0], e2[0]), pk_sub(RI[kb][0], i2[0]));
                float s1 = sq2(pk_sub(RR[kb][1], e2[1]), pk_sub(RI[kb][1], i2[1]));
                float s2 = sq2(pk_sub(RR[kb][2], e2[2]), pk_sub(RI[kb][2], i2[2]));
                float s3 = sq2(pk_sub(RR[kb][3], e2[3]), pk_sub(RI[kb][3], i2[3]));
                float v = (s0 + s1) + (s2 + s3);
                v = dpp_xor_add<0xB1>(v);            // xor1
                v = dpp_xor_add<0x4E>(v);            // xor2
                v = dpp_xor_add<0x141>(v);           // xor4 via row_half_mirror
                r[kb] = v;
            }
            float sel = (dg == 0) ? r[0] : (dg == 1) ? r[1]
                      : (dg == 2) ? r[2] : r[3];
            vout[i] = GAMMA_F - sel;
        }
        if (dg < 4) *(v4f*)(obase + grp * 4) = vout;  // 16B segment per batch row
    }
}

extern "C" void kernel_launch(void* const* d_in, const int* in_sizes, int n_in,
                              void* d_out, int out_size, void* d_ws, size_t ws_size,
                              hipStream_t stream) {
    const int*   facts = (const int*)d_in[0];
    const float* ent   = (const float*)d_in[1];
    const float* rel   = (const float*)d_in[2];
    float*       out   = (float*)d_out;
    (void)d_ws; (void)ws_size;

    // 3125 blocks x 32 entities/block = 100000 exactly
    rotate_dist_fused<<<dim3(NUM_E / 32), dim3(256), 0, stream>>>(facts, ent, rel, out);
}

// Round 5
// 119.448 us; speedup vs baseline: 4.1987x; 1.0171x over previous
//
#include <hip/hip_runtime.h>
#include <math.h>

#define NUM_E   100000
#define GAMMA_F 12.0f
#define EMB_RANGE_F 0.21875f                       // (12+2)/64
#define INV_TWO_EMB (1.0f / (2.0f * EMB_RANGE_F))  // rev = r * this = phase/(2pi)

typedef float v4f __attribute__((ext_vector_type(4)));
typedef float v2f __attribute__((ext_vector_type(2)));

// ---- packed-f32 VALU (VOP3P): 2 dims per instruction ----
static __device__ __forceinline__ v2f pk_sub(v2f a, v2f b) {
    v2f d;
    asm("v_pk_add_f32 %0, %1, %2 neg_lo:[0,1] neg_hi:[0,1]"
        : "=v"(d) : "v"(a), "v"(b));
    return d;
}
static __device__ __forceinline__ v2f pk_mul(v2f a, v2f b) {
    v2f d;
    asm("v_pk_mul_f32 %0, %1, %2" : "=v"(d) : "v"(a), "v"(b));
    return d;
}
static __device__ __forceinline__ v2f pk_fma(v2f a, v2f b, v2f c) {
    v2f d;
    asm("v_pk_fma_f32 %0, %1, %2, %3" : "=v"(d) : "v"(a), "v"(b), "v"(c));
    return d;
}
static __device__ __forceinline__ float sq2(v2f dx, v2f dy) {
    v2f sq = pk_fma(dy, dy, pk_mul(dx, dx));
    return __builtin_amdgcn_sqrtf(sq.x) + __builtin_amdgcn_sqrtf(sq.y);
}
static __device__ __forceinline__ v2f lo2(v4f v) { return __builtin_shufflevector(v, v, 0, 1); }
static __device__ __forceinline__ v2f hi2(v4f v) { return __builtin_shufflevector(v, v, 2, 3); }

// cross-lane add via DPP (VALU pipe, no DS, no lgkm wait)
// 0xB1 = quad_perm [1,0,3,2] (xor1), 0x4E = quad_perm [2,3,0,1] (xor2),
// 0x141 = row_half_mirror: valid xor4 substitute AFTER xor1+xor2 (verified
// passing in R8-R10).
template <int CTRL>
static __device__ __forceinline__ float dpp_xor_add(float x) {
    int y = __builtin_amdgcn_update_dpp(0, __float_as_int(x), CTRL, 0xF, 0xF, true);
    return x + __int_as_float(y);
}

// full per-entity distance for this lane's 4 batches x 8 dims, reduced over dg
static __device__ __forceinline__ float dist_entity(
        v4f er0, v4f er1, v4f ei0, v4f ei1,
        const v2f RR[4][4], const v2f RI[4][4], int dg) {
    v2f e2[4] = { lo2(er0), hi2(er0), lo2(er1), hi2(er1) };
    v2f i2[4] = { lo2(ei0), hi2(ei0), lo2(ei1), hi2(ei1) };
    float r[4];
#pragma unroll
    for (int kb = 0; kb < 4; ++kb) {
        float s0 = sq2(pk_sub(RR[kb][0], e2[0]), pk_sub(RI[kb][0], i2[0]));
        float s1 = sq2(pk_sub(RR[kb][1], e2[1]), pk_sub(RI[kb][1], i2[1]));
        float s2 = sq2(pk_sub(RR[kb][2], e2[2]), pk_sub(RI[kb][2], i2[2]));
        float s3 = sq2(pk_sub(RR[kb][3], e2[3]), pk_sub(RI[kb][3], i2[3]));
        float v = (s0 + s1) + (s2 + s3);
        v = dpp_xor_add<0xB1>(v);            // xor1
        v = dpp_xor_add<0x4E>(v);            // xor2
        v = dpp_xor_add<0x141>(v);           // xor4 via row_half_mirror
        r[kb] = v;
    }
    float sel = (dg == 0) ? r[0] : (dg == 1) ? r[1]
              : (dg == 2) ? r[2] : r[3];
    return GAMMA_F - sel;
}

#define LOADE(d0, d1, d2, d3, EIDX) do {                         \
    const float* _p = ent + (size_t)(EIDX) * 128 + dg * 8;       \
    d0 = *(const v4f*)(_p);      d1 = *(const v4f*)(_p + 4);     \
    d2 = *(const v4f*)(_p + 64); d3 = *(const v4f*)(_p + 68); } while (0)

// R11 = R10 + software-pipelined entity stream.
// R10 diagnosis: WRITE=13MB (no spill), VALUBusy 59%, dispatch 48us vs ~20us
// issue floor -> latency-stall bound: each 4-entity group's 16 dwordx4 loads
// issued right before first use (L3 round-trip ~450cy exposed per group).
// Fix: pair-wise processing with 1-deep A/B register double-buffer; every
// entity's loads issue one full entity-compute (~490cy) before consumption.
// First entity load issued BEFORE __syncthreads (hidden under barrier + LDS
// reads). Live set ~115 VGPR under the (256,2)=128 cap -> 4 waves/SIMD; a
// non-stalling wave64 stream saturates issue, so busy% should rise anyway.
__global__ __launch_bounds__(256, 2) void rotate_dist_fused(
        const int*   __restrict__ facts,
        const float* __restrict__ ent,
        const float* __restrict__ rel,
        float*       __restrict__ out) {
    __shared__ __align__(16) float rot_lds[16 * 64 * 4];   // 16 KB

    const int t    = threadIdx.x;
    const int lane = t & 63;
    const int wv   = t >> 6;            // doubles as kb in the prologue
    const int bg   = lane >> 3;         // batches 4bg..4bg+3
    const int dg   = lane & 7;          // dims 8dg..8dg+7

    // ---- prologue: rot table into LDS (wave wv computes kb=wv slots) ----
    {
        const int b  = bg * 4 + wv;     // this thread's batch row
        const int f0 = facts[b * 3 + 0];
        const int f1 = facts[b * 3 + 1];
        const float* hp = ent + (size_t)f0 * 128 + dg * 8;
        const float* rp = rel + (size_t)f1 * 64  + dg * 8;
        v4f hre0 = *(const v4f*)(hp);
        v4f hre1 = *(const v4f*)(hp + 4);
        v4f him0 = *(const v4f*)(hp + 64);
        v4f him1 = *(const v4f*)(hp + 68);
        v4f ph0  = *(const v4f*)(rp);
        v4f ph1  = *(const v4f*)(rp + 4);
        v4f rr0, rr1, ri0, ri1;
#pragma unroll
        for (int j = 0; j < 4; ++j) {
            float rev0 = ph0[j] * INV_TWO_EMB;       // phase/(2pi) in [-0.5,0.5]
            float s0 = __builtin_amdgcn_sinf(rev0);  // v_sin_f32: revolutions
            float c0 = __builtin_amdgcn_cosf(rev0);
            rr0[j] = hre0[j] * c0 - him0[j] * s0;
            ri0[j] = hre0[j] * s0 + him0[j] * c0;
            float rev1 = ph1[j] * INV_TWO_EMB;
            float s1 = __builtin_amdgcn_sinf(rev1);
            float c1 = __builtin_amdgcn_cosf(rev1);
            rr1[j] = hre1[j] * c1 - him1[j] * s1;
            ri1[j] = hre1[j] * s1 + him1[j] * c1;
        }
        // layout: ((kb*4 + part)*64 + lane)*4 ; parts: re-lo, re-hi, im-lo, im-hi
        float* wbase = rot_lds + (wv * 4) * 256 + lane * 4;
        *(v4f*)(wbase + 0 * 256) = rr0;
        *(v4f*)(wbase + 1 * 256) = rr1;
        *(v4f*)(wbase + 2 * 256) = ri0;
        *(v4f*)(wbase + 3 * 256) = ri1;
    }

    const int e0 = blockIdx.x * 32 + wv * 8;

    // issue first entity load NOW: hides under the barrier + RR/RI LDS reads
    v4f A0, A1, A2, A3, B0, B1, B2, B3;
    LOADE(A0, A1, A2, A3, e0);

    __syncthreads();

    const float* rbase = rot_lds + lane * 4;
    float* obase = out + (size_t)(bg * 4 + (dg & 3)) * NUM_E + e0;

    // rot fragments LDS -> registers ONCE (64 VGPRs, resident for the kernel)
    v2f RR[4][4], RI[4][4];
#pragma unroll
    for (int kb = 0; kb < 4; ++kb) {
        v4f a = *(const v4f*)(rbase + (kb * 4 + 0) * 256);
        v4f b = *(const v4f*)(rbase + (kb * 4 + 1) * 256);
        v4f c = *(const v4f*)(rbase + (kb * 4 + 2) * 256);
        v4f d = *(const v4f*)(rbase + (kb * 4 + 3) * 256);
        RR[kb][0] = lo2(a); RR[kb][1] = hi2(a); RR[kb][2] = lo2(b); RR[kb][3] = hi2(b);
        RI[kb][0] = lo2(c); RI[kb][1] = hi2(c); RI[kb][2] = lo2(d); RI[kb][3] = hi2(d);
    }

    const int elast = NUM_E - 1;        // prefetch clamp for the grid's last wave

#pragma unroll 1
    for (int g = 0; g < 2; ++g) {
        const int eb = e0 + g * 4;
        v4f vout;
        LOADE(B0, B1, B2, B3, eb + 1);                   // prefetch e+1
        vout[0] = dist_entity(A0, A1, A2, A3, RR, RI, dg);
        LOADE(A0, A1, A2, A3, eb + 2);                   // prefetch e+2
        vout[1] = dist_entity(B0, B1, B2, B3, RR, RI, dg);
        LOADE(B0, B1, B2, B3, eb + 3);                   // prefetch e+3
        vout[2] = dist_entity(A0, A1, A2, A3, RR, RI, dg);
        {
            int en = eb + 4; en = (en > elast) ? elast : en;
            LOADE(A0, A1, A2, A3, en);                   // prefetch next group
        }
        vout[3] = dist_entity(B0, B1, B2, B3, RR, RI, dg);
        if (dg < 4) *(v4f*)(obase + g * 4) = vout;       // 16B coalesced segment
    }
}

extern "C" void kernel_launch(void* const* d_in, const int* in_sizes, int n_in,
                              void* d_out, int out_size, void* d_ws, size_t ws_size,
                              hipStream_t stream) {
    const int*   facts = (const int*)d_in[0];
    const float* ent   = (const float*)d_in[1];
    const float* rel   = (const float*)d_in[2];
    float*       out   = (float*)d_out;
    (void)d_ws; (void)ws_size;

    // 3125 blocks x 32 entities/block = 100000 exactly
    rotate_dist_fused<<<dim3(NUM_E / 32), dim3(256), 0, stream>>>(facts, ent, rel, out);
}